// Round 6
// baseline (571.946 us; speedup 1.0000x reference)
//
#include <hip/hip_runtime.h>
#include <math.h>

// Problem constants: B=4, N=256, C=512, H=8, Dh=64
#define BB 4
#define NN 256
#define CC 512
#define HH 8
#define DH 64

typedef __attribute__((ext_vector_type(8))) short bf16x8;
typedef __attribute__((ext_vector_type(4))) float f32x4;

__device__ inline unsigned short f2bf(float f) {
  unsigned u = __float_as_uint(f);
  u += 0x7FFFu + ((u >> 16) & 1u);  // round-to-nearest-even
  return (unsigned short)(u >> 16);
}
__device__ inline float bf2f(unsigned short s) {
  return __uint_as_float((unsigned)s << 16);
}

// ---------------------------------------------------------------------------
// fp32 -> (hi, lo) bf16 split for x, w_qkv, w_proj in ONE launch.
// ---------------------------------------------------------------------------
__global__ __launch_bounds__(256) void cvt_all(
    const float* __restrict__ x, const float* __restrict__ wq,
    const float* __restrict__ wp, unsigned short* __restrict__ xh,
    unsigned short* __restrict__ xl, unsigned short* __restrict__ wqh,
    unsigned short* __restrict__ wql, unsigned short* __restrict__ wph,
    unsigned short* __restrict__ wpl) {
  const int nX = BB * NN * CC, nWq = 3 * CC * CC;
  int i = (blockIdx.x * 256 + threadIdx.x) * 4;
  const float* src;
  unsigned short *dh, *dl;
  int off;
  if (i < nX) {
    src = x; dh = xh; dl = xl; off = i;
  } else if (i < nX + nWq) {
    src = wq; dh = wqh; dl = wql; off = i - nX;
  } else {
    src = wp; dh = wph; dl = wpl; off = i - nX - nWq;
  }
  float4 f = *(const float4*)(src + off);
  float fa[4] = {f.x, f.y, f.z, f.w};
  ushort4 hv, lv;
  unsigned short* hp = (unsigned short*)&hv;
  unsigned short* lp = (unsigned short*)&lv;
#pragma unroll
  for (int j = 0; j < 4; j++) {
    unsigned short hb = f2bf(fa[j]);
    hp[j] = hb;
    lp[j] = f2bf(fa[j] - bf2f(hb));
  }
  *(ushort4*)(dh + off) = hv;
  *(ushort4*)(dl + off) = lv;
}

// ---------------------------------------------------------------------------
// MFMA GEMM, bf16 hi/lo split (3 products): C = A * B^T (+bias).
// Tile 32 x (32*TJ), 256 thr = 4 waves in 2x2; wave = 16 x (16*TJ).
// Small tiles -> high block count (qkv: 768, proj: 512) for occupancy.
// ---------------------------------------------------------------------------
template <int TJ, bool BIAS>
__global__ __launch_bounds__(256, 4) void gemm_mfma(
    const unsigned short* __restrict__ Ah, const unsigned short* __restrict__ Al,
    const unsigned short* __restrict__ Bh, const unsigned short* __restrict__ Bl,
    const float* __restrict__ bias, float* __restrict__ C, int M, int N,
    int K) {
  __shared__ unsigned short sAh[32][40], sAl[32][40];
  __shared__ unsigned short sBh[32 * TJ][40], sBl[32 * TJ][40];
  const int t = threadIdx.x;
  const int lane = t & 63;
  const int w = t >> 6;
  const int bm = blockIdx.y * 32;
  const int bn = blockIdx.x * (32 * TJ);
  const int wr = (w >> 1) * 16;
  const int wc = (w & 1) * (16 * TJ);
  const int quad = lane >> 4;
  const int l16 = lane & 15;

  f32x4 acc[TJ];
#pragma unroll
  for (int j = 0; j < TJ; j++) {
    acc[j][0] = 0.f; acc[j][1] = 0.f; acc[j][2] = 0.f; acc[j][3] = 0.f;
  }

  // staging decode (compile-time folds)
  const int aHalf = t >> 7;        // 0=hi 1=lo
  const int aR = (t >> 2) & 31;
  const int aC8 = (t & 3) * 8;

  for (int k0 = 0; k0 < K; k0 += 32) {
    __syncthreads();
    {
      const unsigned short* src =
          (aHalf ? Al : Ah) + (size_t)(bm + aR) * K + k0 + aC8;
      uint4 vv = *(const uint4*)src;
      if (aHalf) *(uint4*)&sAl[aR][aC8] = vv;
      else       *(uint4*)&sAh[aR][aC8] = vv;
    }
#pragma unroll
    for (int i = 0; i < TJ; i++) {
      int s = t + 256 * i;
      int half = s / (128 * TJ);
      int rem = s % (128 * TJ);
      int r = rem >> 2;
      int c8 = (rem & 3) * 8;
      const unsigned short* src =
          (half ? Bl : Bh) + (size_t)(bn + r) * K + k0 + c8;
      uint4 vv = *(const uint4*)src;
      if (half) *(uint4*)&sBl[r][c8] = vv;
      else      *(uint4*)&sBh[r][c8] = vv;
    }
    __syncthreads();

    bf16x8 ah = *(const bf16x8*)&sAh[wr + l16][quad * 8];
    bf16x8 al = *(const bf16x8*)&sAl[wr + l16][quad * 8];
#pragma unroll
    for (int j = 0; j < TJ; j++) {
      bf16x8 bh = *(const bf16x8*)&sBh[wc + j * 16 + l16][quad * 8];
      bf16x8 bl = *(const bf16x8*)&sBl[wc + j * 16 + l16][quad * 8];
      acc[j] = __builtin_amdgcn_mfma_f32_16x16x32_bf16(ah, bh, acc[j], 0, 0, 0);
      acc[j] = __builtin_amdgcn_mfma_f32_16x16x32_bf16(ah, bl, acc[j], 0, 0, 0);
      acc[j] = __builtin_amdgcn_mfma_f32_16x16x32_bf16(al, bh, acc[j], 0, 0, 0);
    }
  }

  // epilogue: C/D layout col=lane&15, row=quad*4+reg
#pragma unroll
  for (int j = 0; j < TJ; j++) {
    int n = bn + wc + j * 16 + l16;
    float bv = BIAS ? bias[n] : 0.f;
#pragma unroll
    for (int r = 0; r < 4; r++) {
      int m = bm + wr + quad * 4 + r;
      C[(size_t)m * N + n] = acc[j][r] + bv;
    }
  }
}

// ---------------------------------------------------------------------------
// Fused Fourier attention, key-split x2. Grid (32, H, B): x = qc*2 + ks.
// 512 thr = 8 waves, 2 queries/wave, 16 queries/block, 128 keys (2 tiles).
// LDS tiles XOR-swizzled (group ^ row&15) so lane=row b128 reads spread
// bank starts. Staging pre-scales q'=R*q, k'=R*k (NO epsilon: with exact
// bitwise q_d==k_d collisions, D=0 -> den=0; since |sin x|<=|x| per factor,
// den==0 implies num==0 and the true score is negligible -> guard the one
// division with den!=0 instead of perturbing every D).
// score = (PI sin(D) / PI D) * R^64.
// ---------------------------------------------------------------------------
__global__ __launch_bounds__(512, 8) void fourier_attn(
    const float* __restrict__ qkv, const float* __restrict__ paramR,
    float* __restrict__ acc0, float* __restrict__ acc1,
    float* __restrict__ S0, float* __restrict__ S1) {
  __shared__ float Kt[64][64];    // [key][dim-group swizzled]
  __shared__ float VtT[64][64];   // [dim][key-group swizzled]
  __shared__ float Qs[16][64];    // scaled queries
  __shared__ float A4[8][64][2];  // [wave][key][q]

  const int t = threadIdx.x;
  const int lane = t & 63;
  const int wv = t >> 6;
  const int qc = blockIdx.x >> 1;
  const int ks = blockIdx.x & 1;
  const int h = blockIdx.y;
  const int b = blockIdx.z;
  const float R = paramR[0];
  const float R64 = __powf(R * R, 32.0f);

  const float* base = qkv + (size_t)b * NN * (3 * CC) + h * DH;

  if (t < 256) {
    int r = t >> 4;
    int c4 = (t & 15) << 2;
    float4 qv = *(const float4*)(base + (size_t)(qc * 16 + r) * (3 * CC) + c4);
    qv.x *= R; qv.y *= R; qv.z *= R; qv.w *= R;
    *(float4*)&Qs[r][c4] = qv;
  }

  const int qi0 = wv * 2, qi1 = wv * 2 + 1;
  const int sw = lane & 15;
  float Sp[2] = {0.f, 0.f};
  float oacc[2] = {0.f, 0.f};

  for (int jt2 = 0; jt2 < 2; jt2++) {
    const int jt = ks * 2 + jt2;
    __syncthreads();
#pragma unroll
    for (int u0 = 0; u0 < 2; u0++) {
      int u = t + 512 * u0;
      int r = u >> 4;        // key row 0..63
      int g = u & 15;        // dim group
      int c4 = g << 2;
      const float* krow = base + (size_t)(jt * 64 + r) * (3 * CC) + CC;
      float4 kv = *(const float4*)(krow + c4);
      kv.x *= R; kv.y *= R; kv.z *= R; kv.w *= R;
      *(float4*)&Kt[r][(g ^ (r & 15)) << 2] = kv;
      const float* vrow = base + (size_t)(jt * 64 + r) * (3 * CC) + 2 * CC;
      float4 vv = *(const float4*)(vrow + c4);
      int kg = r >> 2, ko = r & 3;
      float va[4] = {vv.x, vv.y, vv.z, vv.w};
#pragma unroll
      for (int i = 0; i < 4; i++)
        VtT[c4 + i][((kg ^ ((c4 + i) & 15)) << 2) + ko] = va[i];
    }
    __syncthreads();

    // ---- score phase: lane = key
    float nm[2][2] = {{1.f, 1.f}, {1.f, 1.f}};
    float dn[2][2] = {{1.f, 1.f}, {1.f, 1.f}};
#pragma unroll
    for (int d4 = 0; d4 < 16; d4++) {
      const int p = d4 & 1;
      float4 k4 = *(const float4*)&Kt[lane][(d4 ^ sw) << 2];
      float4 qa = *(const float4*)&Qs[qi0][d4 << 2];
      float4 qb = *(const float4*)&Qs[qi1][d4 << 2];
      float ka[4] = {k4.x, k4.y, k4.z, k4.w};
      float q0a[4] = {qa.x, qa.y, qa.z, qa.w};
      float q1a[4] = {qb.x, qb.y, qb.z, qb.w};
#pragma unroll
      for (int j = 0; j < 4; j++) {
        float D0 = q0a[j] - ka[j];  // = R*(q-k), exact for R=1
        float D1 = q1a[j] - ka[j];
        nm[0][p] *= __sinf(D0);
        dn[0][p] *= D0;
        nm[1][p] *= __sinf(D1);
        dn[1][p] *= D1;
      }
    }
#pragma unroll
    for (int q = 0; q < 2; q++) {
      float num = nm[q][0] * nm[q][1];
      float den = dn[q][0] * dn[q][1];
      float sc = (den != 0.f) ? (num / den) * R64 : 0.f;
      float s2 = sc * sc;
      float a4 = s2 * s2;
      Sp[q] += a4;
      A4[wv][lane][q] = a4;  // same-wave RAW with AV below
    }

    // ---- AV phase: lane = dim
#pragma unroll
    for (int kg = 0; kg < 16; kg++) {
      float4 v4 = *(const float4*)&VtT[lane][(kg ^ sw) << 2];
      float4 a01 = *(const float4*)&A4[wv][kg * 4 + 0][0];
      float4 a23 = *(const float4*)&A4[wv][kg * 4 + 2][0];
      oacc[0] = fmaf(a01.x, v4.x, oacc[0]);
      oacc[1] = fmaf(a01.y, v4.x, oacc[1]);
      oacc[0] = fmaf(a01.z, v4.y, oacc[0]);
      oacc[1] = fmaf(a01.w, v4.y, oacc[1]);
      oacc[0] = fmaf(a23.x, v4.z, oacc[0]);
      oacc[1] = fmaf(a23.y, v4.z, oacc[1]);
      oacc[0] = fmaf(a23.z, v4.w, oacc[0]);
      oacc[1] = fmaf(a23.w, v4.w, oacc[1]);
    }
  }

  // ---- store partials
  float* accp = ks ? acc1 : acc0;
  float* Sg = ks ? S1 : S0;
#pragma unroll
  for (int q = 0; q < 2; q++) {
    float s = Sp[q];
#pragma unroll
    for (int off = 32; off > 0; off >>= 1) s += __shfl_xor(s, off, 64);
    int n = qc * 16 + wv * 2 + q;
    accp[(size_t)(b * NN + n) * CC + h * DH + lane] = oacc[q];
    if (lane == 0) Sg[((b * HH + h) << 8) + n] = s;
  }
}

// ---------------------------------------------------------------------------
// Combine key-split partials, normalize, emit hi/lo bf16 for the proj GEMM.
// ---------------------------------------------------------------------------
__global__ __launch_bounds__(256) void normalize_hilo(
    const float* __restrict__ acc0, const float* __restrict__ acc1,
    const float* __restrict__ S0, const float* __restrict__ S1,
    unsigned short* __restrict__ aoh, unsigned short* __restrict__ aol) {
  int idx = (blockIdx.x * 256 + threadIdx.x) * 4;
  int m = idx >> 9;
  int c = idx & 511;
  int b = m >> 8, n = m & 255, h = c >> 6;
  int si = ((b * HH + h) << 8) + n;
  float s = S0[si] + S1[si] + 1e-6f;
  float4 a = *(const float4*)(acc0 + idx);
  float4 a1 = *(const float4*)(acc1 + idx);
  float oa[4] = {(a.x + a1.x) / s, (a.y + a1.y) / s, (a.z + a1.z) / s,
                 (a.w + a1.w) / s};
  ushort4 hv, lv;
  unsigned short* hp = (unsigned short*)&hv;
  unsigned short* lp = (unsigned short*)&lv;
#pragma unroll
  for (int j = 0; j < 4; j++) {
    unsigned short hb = f2bf(oa[j]);
    hp[j] = hb;
    lp[j] = f2bf(oa[j] - bf2f(hb));
  }
  *(ushort4*)(aoh + idx) = hv;
  *(ushort4*)(aol + idx) = lv;
}

// ---------------------------------------------------------------------------
extern "C" void kernel_launch(void* const* d_in, const int* in_sizes, int n_in,
                              void* d_out, int out_size, void* d_ws,
                              size_t ws_size, hipStream_t stream) {
  const float* x = (const float*)d_in[0];       // (B,N,C)
  const float* w_qkv = (const float*)d_in[1];   // (3C, C)
  const float* w_proj = (const float*)d_in[2];  // (C, C)
  const float* b_proj = (const float*)d_in[3];  // (C,)
  const float* paramR = (const float*)d_in[4];  // (1,)
  float* outp = (float*)d_out;                  // (B,N,C)

  const int nX = BB * NN * CC;   // 524288
  const int nWq = 3 * CC * CC;   // 786432
  const int nWp = CC * CC;       // 262144

  // ws layout (shorts), ~14.7 MB total:
  unsigned short* xh = (unsigned short*)d_ws;
  unsigned short* xl = xh + nX;
  unsigned short* wqh = xl + nX;
  unsigned short* wql = wqh + nWq;
  unsigned short* wph = wql + nWq;
  unsigned short* wpl = wph + nWp;
  unsigned short* aoh = wpl + nWp;
  unsigned short* aol = aoh + nX;
  float* qkv_ws = (float*)(aol + nX);  // 1024*1536 fp32

  // acc/S alias the xh..wql region (dead after the qkv GEMM, rewritten
  // in-order on every replay): 2*nX + 16K floats < that region's 2.6M shorts.
  float* acc0 = (float*)d_ws;
  float* acc1 = acc0 + nX;
  float* S0 = acc1 + nX;
  float* S1 = S0 + BB * HH * NN;

  // 1) hi/lo conversions (single launch)
  cvt_all<<<(nX + nWq + nWp) / 1024, 256, 0, stream>>>(
      x, w_qkv, w_proj, xh, xl, wqh, wql, wph, wpl);

  // 2) qkv = x @ w_qkv^T : M=1024, N=1536, K=512; 32x64 tiles -> 768 blocks
  gemm_mfma<2, false><<<dim3(3 * CC / 64, BB * NN / 32), 256, 0, stream>>>(
      xh, xl, wqh, wql, nullptr, qkv_ws, BB * NN, 3 * CC, CC);

  // 3) fused fourier attention, key-split x2 -> partial acc/S
  fourier_attn<<<dim3(32, HH, BB), 512, 0, stream>>>(qkv_ws, paramR, acc0,
                                                     acc1, S0, S1);

  // 4) combine + normalize + hi/lo split
  normalize_hilo<<<nX / 1024, 256, 0, stream>>>(acc0, acc1, S0, S1, aoh, aol);

  // 5) out = attn @ w_proj^T + b_proj : 32x32 tiles -> 512 blocks
  gemm_mfma<1, true><<<dim3(CC / 32, BB * NN / 32), 256, 0, stream>>>(
      aoh, aol, wph, wpl, b_proj, outp, BB * NN, CC, CC);
}

// Round 7
// 310.664 us; speedup vs baseline: 1.8410x; 1.8410x over previous
//
#include <hip/hip_runtime.h>
#include <math.h>

// Problem constants: B=4, N=256, C=512, H=8, Dh=64
#define BB 4
#define NN 256
#define CC 512
#define HH 8
#define DH 64

typedef __attribute__((ext_vector_type(8))) short bf16x8;
typedef __attribute__((ext_vector_type(4))) float f32x4;

__device__ inline unsigned short f2bf(float f) {
  unsigned u = __float_as_uint(f);
  u += 0x7FFFu + ((u >> 16) & 1u);  // round-to-nearest-even
  return (unsigned short)(u >> 16);
}
__device__ inline float bf2f(unsigned short s) {
  return __uint_as_float((unsigned)s << 16);
}

// ---------------------------------------------------------------------------
// fp32 -> (hi, lo) bf16 split for x, w_qkv, w_proj in ONE launch.
// ---------------------------------------------------------------------------
__global__ __launch_bounds__(256) void cvt_all(
    const float* __restrict__ x, const float* __restrict__ wq,
    const float* __restrict__ wp, unsigned short* __restrict__ xh,
    unsigned short* __restrict__ xl, unsigned short* __restrict__ wqh,
    unsigned short* __restrict__ wql, unsigned short* __restrict__ wph,
    unsigned short* __restrict__ wpl) {
  const int nX = BB * NN * CC, nWq = 3 * CC * CC;
  int i = (blockIdx.x * 256 + threadIdx.x) * 4;
  const float* src;
  unsigned short *dh, *dl;
  int off;
  if (i < nX) {
    src = x; dh = xh; dl = xl; off = i;
  } else if (i < nX + nWq) {
    src = wq; dh = wqh; dl = wql; off = i - nX;
  } else {
    src = wp; dh = wph; dl = wpl; off = i - nX - nWq;
  }
  float4 f = *(const float4*)(src + off);
  float fa[4] = {f.x, f.y, f.z, f.w};
  ushort4 hv, lv;
  unsigned short* hp = (unsigned short*)&hv;
  unsigned short* lp = (unsigned short*)&lv;
#pragma unroll
  for (int j = 0; j < 4; j++) {
    unsigned short hb = f2bf(fa[j]);
    hp[j] = hb;
    lp[j] = f2bf(fa[j] - bf2f(hb));
  }
  *(ushort4*)(dh + off) = hv;
  *(ushort4*)(dl + off) = lv;
}

// ---------------------------------------------------------------------------
// MFMA GEMM, bf16 hi/lo split (3 products): C = A * B^T (+bias).
// Tile 32 x (32*TJ), 256 thr = 4 waves in 2x2; wave = 16 x (16*TJ).
// Small tiles -> high block count (qkv: 768, proj: 512) for occupancy.
// ---------------------------------------------------------------------------
template <int TJ, bool BIAS>
__global__ __launch_bounds__(256, 4) void gemm_mfma(
    const unsigned short* __restrict__ Ah, const unsigned short* __restrict__ Al,
    const unsigned short* __restrict__ Bh, const unsigned short* __restrict__ Bl,
    const float* __restrict__ bias, float* __restrict__ C, int M, int N,
    int K) {
  __shared__ unsigned short sAh[32][40], sAl[32][40];
  __shared__ unsigned short sBh[32 * TJ][40], sBl[32 * TJ][40];
  const int t = threadIdx.x;
  const int lane = t & 63;
  const int w = t >> 6;
  const int bm = blockIdx.y * 32;
  const int bn = blockIdx.x * (32 * TJ);
  const int wr = (w >> 1) * 16;
  const int wc = (w & 1) * (16 * TJ);
  const int quad = lane >> 4;
  const int l16 = lane & 15;

  f32x4 acc[TJ];
#pragma unroll
  for (int j = 0; j < TJ; j++) {
    acc[j][0] = 0.f; acc[j][1] = 0.f; acc[j][2] = 0.f; acc[j][3] = 0.f;
  }

  // staging decode (compile-time folds)
  const int aHalf = t >> 7;        // 0=hi 1=lo
  const int aR = (t >> 2) & 31;
  const int aC8 = (t & 3) * 8;

  for (int k0 = 0; k0 < K; k0 += 32) {
    __syncthreads();
    {
      const unsigned short* src =
          (aHalf ? Al : Ah) + (size_t)(bm + aR) * K + k0 + aC8;
      uint4 vv = *(const uint4*)src;
      if (aHalf) *(uint4*)&sAl[aR][aC8] = vv;
      else       *(uint4*)&sAh[aR][aC8] = vv;
    }
#pragma unroll
    for (int i = 0; i < TJ; i++) {
      int s = t + 256 * i;
      int half = s / (128 * TJ);
      int rem = s % (128 * TJ);
      int r = rem >> 2;
      int c8 = (rem & 3) * 8;
      const unsigned short* src =
          (half ? Bl : Bh) + (size_t)(bn + r) * K + k0 + c8;
      uint4 vv = *(const uint4*)src;
      if (half) *(uint4*)&sBl[r][c8] = vv;
      else      *(uint4*)&sBh[r][c8] = vv;
    }
    __syncthreads();

    bf16x8 ah = *(const bf16x8*)&sAh[wr + l16][quad * 8];
    bf16x8 al = *(const bf16x8*)&sAl[wr + l16][quad * 8];
#pragma unroll
    for (int j = 0; j < TJ; j++) {
      bf16x8 bh = *(const bf16x8*)&sBh[wc + j * 16 + l16][quad * 8];
      bf16x8 bl = *(const bf16x8*)&sBl[wc + j * 16 + l16][quad * 8];
      acc[j] = __builtin_amdgcn_mfma_f32_16x16x32_bf16(ah, bh, acc[j], 0, 0, 0);
      acc[j] = __builtin_amdgcn_mfma_f32_16x16x32_bf16(ah, bl, acc[j], 0, 0, 0);
      acc[j] = __builtin_amdgcn_mfma_f32_16x16x32_bf16(al, bh, acc[j], 0, 0, 0);
    }
  }

  // epilogue: C/D layout col=lane&15, row=quad*4+reg
#pragma unroll
  for (int j = 0; j < TJ; j++) {
    int n = bn + wc + j * 16 + l16;
    float bv = BIAS ? bias[n] : 0.f;
#pragma unroll
    for (int r = 0; r < 4; r++) {
      int m = bm + wr + quad * 4 + r;
      C[(size_t)m * N + n] = acc[j][r] + bv;
    }
  }
}

// ---------------------------------------------------------------------------
// Fused Fourier attention, key-split x2. Grid (32, H, B): x = qc*2 + ks.
// 512 thr = 8 waves, 2 queries/wave, 16 queries/block, 128 keys (2 tiles).
// __launch_bounds__(512, 4): VGPR cap 128 (kernel needs ~56). (512,8) capped
// at 64 -> compiler spilled everything to scratch -> 1.7 GB HBM traffic and
// 477 us (round-6 regression). DO NOT raise the min-waves arg here.
// LDS tiles XOR-swizzled (group ^ row&15). Staging pre-scales q'=R*q, k'=R*k.
// Bitwise q_d==k_d collision -> den==0 -> guarded division (|sin x|<=|x|
// implies num==0 too; true score negligible).
// ---------------------------------------------------------------------------
__global__ __launch_bounds__(512, 4) void fourier_attn(
    const float* __restrict__ qkv, const float* __restrict__ paramR,
    float* __restrict__ acc0, float* __restrict__ acc1,
    float* __restrict__ S0, float* __restrict__ S1) {
  __shared__ float Kt[64][64];    // [key][dim-group swizzled]
  __shared__ float VtT[64][64];   // [dim][key-group swizzled]
  __shared__ float Qs[16][64];    // scaled queries
  __shared__ float A4[8][64][2];  // [wave][key][q]

  const int t = threadIdx.x;
  const int lane = t & 63;
  const int wv = t >> 6;
  const int qc = blockIdx.x >> 1;
  const int ks = blockIdx.x & 1;
  const int h = blockIdx.y;
  const int b = blockIdx.z;
  const float R = paramR[0];
  const float R64 = __powf(R * R, 32.0f);

  const float* base = qkv + (size_t)b * NN * (3 * CC) + h * DH;

  if (t < 256) {
    int r = t >> 4;
    int c4 = (t & 15) << 2;
    float4 qv = *(const float4*)(base + (size_t)(qc * 16 + r) * (3 * CC) + c4);
    qv.x *= R; qv.y *= R; qv.z *= R; qv.w *= R;
    *(float4*)&Qs[r][c4] = qv;
  }

  const int qi0 = wv * 2, qi1 = wv * 2 + 1;
  const int sw = lane & 15;
  float Sp[2] = {0.f, 0.f};
  float oacc[2] = {0.f, 0.f};

  for (int jt2 = 0; jt2 < 2; jt2++) {
    const int jt = ks * 2 + jt2;
    __syncthreads();
#pragma unroll
    for (int u0 = 0; u0 < 2; u0++) {
      int u = t + 512 * u0;
      int r = u >> 4;        // key row 0..63
      int g = u & 15;        // dim group
      int c4 = g << 2;
      const float* krow = base + (size_t)(jt * 64 + r) * (3 * CC) + CC;
      float4 kv = *(const float4*)(krow + c4);
      kv.x *= R; kv.y *= R; kv.z *= R; kv.w *= R;
      *(float4*)&Kt[r][(g ^ (r & 15)) << 2] = kv;
      const float* vrow = base + (size_t)(jt * 64 + r) * (3 * CC) + 2 * CC;
      float4 vv = *(const float4*)(vrow + c4);
      int kg = r >> 2, ko = r & 3;
      float va[4] = {vv.x, vv.y, vv.z, vv.w};
#pragma unroll
      for (int i = 0; i < 4; i++)
        VtT[c4 + i][((kg ^ ((c4 + i) & 15)) << 2) + ko] = va[i];
    }
    __syncthreads();

    // ---- score phase: lane = key
    float nm[2][2] = {{1.f, 1.f}, {1.f, 1.f}};
    float dn[2][2] = {{1.f, 1.f}, {1.f, 1.f}};
#pragma unroll
    for (int d4 = 0; d4 < 16; d4++) {
      const int p = d4 & 1;
      float4 k4 = *(const float4*)&Kt[lane][(d4 ^ sw) << 2];
      float4 qa = *(const float4*)&Qs[qi0][d4 << 2];
      float4 qb = *(const float4*)&Qs[qi1][d4 << 2];
      float ka[4] = {k4.x, k4.y, k4.z, k4.w};
      float q0a[4] = {qa.x, qa.y, qa.z, qa.w};
      float q1a[4] = {qb.x, qb.y, qb.z, qb.w};
#pragma unroll
      for (int j = 0; j < 4; j++) {
        float D0 = q0a[j] - ka[j];  // = R*(q-k), exact for R=1
        float D1 = q1a[j] - ka[j];
        nm[0][p] *= __sinf(D0);
        dn[0][p] *= D0;
        nm[1][p] *= __sinf(D1);
        dn[1][p] *= D1;
      }
    }
#pragma unroll
    for (int q = 0; q < 2; q++) {
      float num = nm[q][0] * nm[q][1];
      float den = dn[q][0] * dn[q][1];
      float sc = (den != 0.f) ? (num / den) * R64 : 0.f;
      float s2 = sc * sc;
      float a4 = s2 * s2;
      Sp[q] += a4;
      A4[wv][lane][q] = a4;  // same-wave RAW with AV below
    }

    // ---- AV phase: lane = dim
#pragma unroll
    for (int kg = 0; kg < 16; kg++) {
      float4 v4 = *(const float4*)&VtT[lane][(kg ^ sw) << 2];
      float4 a01 = *(const float4*)&A4[wv][kg * 4 + 0][0];
      float4 a23 = *(const float4*)&A4[wv][kg * 4 + 2][0];
      oacc[0] = fmaf(a01.x, v4.x, oacc[0]);
      oacc[1] = fmaf(a01.y, v4.x, oacc[1]);
      oacc[0] = fmaf(a01.z, v4.y, oacc[0]);
      oacc[1] = fmaf(a01.w, v4.y, oacc[1]);
      oacc[0] = fmaf(a23.x, v4.z, oacc[0]);
      oacc[1] = fmaf(a23.y, v4.z, oacc[1]);
      oacc[0] = fmaf(a23.z, v4.w, oacc[0]);
      oacc[1] = fmaf(a23.w, v4.w, oacc[1]);
    }
  }

  // ---- store partials
  float* accp = ks ? acc1 : acc0;
  float* Sg = ks ? S1 : S0;
#pragma unroll
  for (int q = 0; q < 2; q++) {
    float s = Sp[q];
#pragma unroll
    for (int off = 32; off > 0; off >>= 1) s += __shfl_xor(s, off, 64);
    int n = qc * 16 + wv * 2 + q;
    accp[(size_t)(b * NN + n) * CC + h * DH + lane] = oacc[q];
    if (lane == 0) Sg[((b * HH + h) << 8) + n] = s;
  }
}

// ---------------------------------------------------------------------------
// Combine key-split partials, normalize, emit hi/lo bf16 for the proj GEMM.
// ---------------------------------------------------------------------------
__global__ __launch_bounds__(256) void normalize_hilo(
    const float* __restrict__ acc0, const float* __restrict__ acc1,
    const float* __restrict__ S0, const float* __restrict__ S1,
    unsigned short* __restrict__ aoh, unsigned short* __restrict__ aol) {
  int idx = (blockIdx.x * 256 + threadIdx.x) * 4;
  int m = idx >> 9;
  int c = idx & 511;
  int b = m >> 8, n = m & 255, h = c >> 6;
  int si = ((b * HH + h) << 8) + n;
  float s = S0[si] + S1[si] + 1e-6f;
  float4 a = *(const float4*)(acc0 + idx);
  float4 a1 = *(const float4*)(acc1 + idx);
  float oa[4] = {(a.x + a1.x) / s, (a.y + a1.y) / s, (a.z + a1.z) / s,
                 (a.w + a1.w) / s};
  ushort4 hv, lv;
  unsigned short* hp = (unsigned short*)&hv;
  unsigned short* lp = (unsigned short*)&lv;
#pragma unroll
  for (int j = 0; j < 4; j++) {
    unsigned short hb = f2bf(oa[j]);
    hp[j] = hb;
    lp[j] = f2bf(oa[j] - bf2f(hb));
  }
  *(ushort4*)(aoh + idx) = hv;
  *(ushort4*)(aol + idx) = lv;
}

// ---------------------------------------------------------------------------
extern "C" void kernel_launch(void* const* d_in, const int* in_sizes, int n_in,
                              void* d_out, int out_size, void* d_ws,
                              size_t ws_size, hipStream_t stream) {
  const float* x = (const float*)d_in[0];       // (B,N,C)
  const float* w_qkv = (const float*)d_in[1];   // (3C, C)
  const float* w_proj = (const float*)d_in[2];  // (C, C)
  const float* b_proj = (const float*)d_in[3];  // (C,)
  const float* paramR = (const float*)d_in[4];  // (1,)
  float* outp = (float*)d_out;                  // (B,N,C)

  const int nX = BB * NN * CC;   // 524288
  const int nWq = 3 * CC * CC;   // 786432
  const int nWp = CC * CC;       // 262144

  // ws layout (shorts), ~14.7 MB total:
  unsigned short* xh = (unsigned short*)d_ws;
  unsigned short* xl = xh + nX;
  unsigned short* wqh = xl + nX;
  unsigned short* wql = wqh + nWq;
  unsigned short* wph = wql + nWq;
  unsigned short* wpl = wph + nWp;
  unsigned short* aoh = wpl + nWp;
  unsigned short* aol = aoh + nX;
  float* qkv_ws = (float*)(aol + nX);  // 1024*1536 fp32

  // acc/S alias the xh..wql region (dead after the qkv GEMM, rewritten
  // in-order on every replay): 2*nX + 16K floats < that region's 2.6M shorts.
  float* acc0 = (float*)d_ws;
  float* acc1 = acc0 + nX;
  float* S0 = acc1 + nX;
  float* S1 = S0 + BB * HH * NN;

  // 1) hi/lo conversions (single launch)
  cvt_all<<<(nX + nWq + nWp) / 1024, 256, 0, stream>>>(
      x, w_qkv, w_proj, xh, xl, wqh, wql, wph, wpl);

  // 2) qkv = x @ w_qkv^T : M=1024, N=1536, K=512; 32x64 tiles -> 768 blocks
  gemm_mfma<2, false><<<dim3(3 * CC / 64, BB * NN / 32), 256, 0, stream>>>(
      xh, xl, wqh, wql, nullptr, qkv_ws, BB * NN, 3 * CC, CC);

  // 3) fused fourier attention, key-split x2 -> partial acc/S
  fourier_attn<<<dim3(32, HH, BB), 512, 0, stream>>>(qkv_ws, paramR, acc0,
                                                     acc1, S0, S1);

  // 4) combine + normalize + hi/lo split
  normalize_hilo<<<nX / 1024, 256, 0, stream>>>(acc0, acc1, S0, S1, aoh, aol);

  // 5) out = attn @ w_proj^T + b_proj : 32x32 tiles -> 512 blocks
  gemm_mfma<1, true><<<dim3(CC / 32, BB * NN / 32), 256, 0, stream>>>(
      aoh, aol, wph, wpl, b_proj, outp, BB * NN, CC, CC);
}

// Round 8
// 251.598 us; speedup vs baseline: 2.2733x; 1.2348x over previous
//
#include <hip/hip_runtime.h>
#include <math.h>

// Problem constants: B=4, N=256, C=512, H=8, Dh=64
#define BB 4
#define NN 256
#define CC 512
#define HH 8
#define DH 64

typedef __attribute__((ext_vector_type(8))) short bf16x8;
typedef __attribute__((ext_vector_type(4))) float f32x4;

__device__ inline unsigned short f2bf(float f) {
  unsigned u = __float_as_uint(f);
  u += 0x7FFFu + ((u >> 16) & 1u);  // round-to-nearest-even
  return (unsigned short)(u >> 16);
}
__device__ inline float bf2f(unsigned short s) {
  return __uint_as_float((unsigned)s << 16);
}

// ---------------------------------------------------------------------------
// fp32 -> (hi, lo) bf16 split for x, w_qkv, w_proj in ONE launch.
// ---------------------------------------------------------------------------
__global__ __launch_bounds__(256) void cvt_all(
    const float* __restrict__ x, const float* __restrict__ wq,
    const float* __restrict__ wp, unsigned short* __restrict__ xh,
    unsigned short* __restrict__ xl, unsigned short* __restrict__ wqh,
    unsigned short* __restrict__ wql, unsigned short* __restrict__ wph,
    unsigned short* __restrict__ wpl) {
  const int nX = BB * NN * CC, nWq = 3 * CC * CC;
  int i = (blockIdx.x * 256 + threadIdx.x) * 4;
  const float* src;
  unsigned short *dh, *dl;
  int off;
  if (i < nX) {
    src = x; dh = xh; dl = xl; off = i;
  } else if (i < nX + nWq) {
    src = wq; dh = wqh; dl = wql; off = i - nX;
  } else {
    src = wp; dh = wph; dl = wpl; off = i - nX - nWq;
  }
  float4 f = *(const float4*)(src + off);
  float fa[4] = {f.x, f.y, f.z, f.w};
  ushort4 hv, lv;
  unsigned short* hp = (unsigned short*)&hv;
  unsigned short* lp = (unsigned short*)&lv;
#pragma unroll
  for (int j = 0; j < 4; j++) {
    unsigned short hb = f2bf(fa[j]);
    hp[j] = hb;
    lp[j] = f2bf(fa[j] - bf2f(hb));
  }
  *(ushort4*)(dh + off) = hv;
  *(ushort4*)(dl + off) = lv;
}

// ---------------------------------------------------------------------------
// MFMA GEMM, bf16 hi/lo split (3 products): C = A * B^T (+bias).
// Tile 32 x (32*TJ), 256 thr = 4 waves in 2x2; wave = 16 x (16*TJ).
// Small tiles -> high block count (qkv: 768, proj: 512) for occupancy.
// ---------------------------------------------------------------------------
template <int TJ, bool BIAS>
__global__ __launch_bounds__(256, 4) void gemm_mfma(
    const unsigned short* __restrict__ Ah, const unsigned short* __restrict__ Al,
    const unsigned short* __restrict__ Bh, const unsigned short* __restrict__ Bl,
    const float* __restrict__ bias, float* __restrict__ C, int M, int N,
    int K) {
  __shared__ unsigned short sAh[32][40], sAl[32][40];
  __shared__ unsigned short sBh[32 * TJ][40], sBl[32 * TJ][40];
  const int t = threadIdx.x;
  const int lane = t & 63;
  const int w = t >> 6;
  const int bm = blockIdx.y * 32;
  const int bn = blockIdx.x * (32 * TJ);
  const int wr = (w >> 1) * 16;
  const int wc = (w & 1) * (16 * TJ);
  const int quad = lane >> 4;
  const int l16 = lane & 15;

  f32x4 acc[TJ];
#pragma unroll
  for (int j = 0; j < TJ; j++) {
    acc[j][0] = 0.f; acc[j][1] = 0.f; acc[j][2] = 0.f; acc[j][3] = 0.f;
  }

  // staging decode (compile-time folds)
  const int aHalf = t >> 7;        // 0=hi 1=lo
  const int aR = (t >> 2) & 31;
  const int aC8 = (t & 3) * 8;

  for (int k0 = 0; k0 < K; k0 += 32) {
    __syncthreads();
    {
      const unsigned short* src =
          (aHalf ? Al : Ah) + (size_t)(bm + aR) * K + k0 + aC8;
      uint4 vv = *(const uint4*)src;
      if (aHalf) *(uint4*)&sAl[aR][aC8] = vv;
      else       *(uint4*)&sAh[aR][aC8] = vv;
    }
#pragma unroll
    for (int i = 0; i < TJ; i++) {
      int s = t + 256 * i;
      int half = s / (128 * TJ);
      int rem = s % (128 * TJ);
      int r = rem >> 2;
      int c8 = (rem & 3) * 8;
      const unsigned short* src =
          (half ? Bl : Bh) + (size_t)(bn + r) * K + k0 + c8;
      uint4 vv = *(const uint4*)src;
      if (half) *(uint4*)&sBl[r][c8] = vv;
      else      *(uint4*)&sBh[r][c8] = vv;
    }
    __syncthreads();

    bf16x8 ah = *(const bf16x8*)&sAh[wr + l16][quad * 8];
    bf16x8 al = *(const bf16x8*)&sAl[wr + l16][quad * 8];
#pragma unroll
    for (int j = 0; j < TJ; j++) {
      bf16x8 bh = *(const bf16x8*)&sBh[wc + j * 16 + l16][quad * 8];
      bf16x8 bl = *(const bf16x8*)&sBl[wc + j * 16 + l16][quad * 8];
      acc[j] = __builtin_amdgcn_mfma_f32_16x16x32_bf16(ah, bh, acc[j], 0, 0, 0);
      acc[j] = __builtin_amdgcn_mfma_f32_16x16x32_bf16(ah, bl, acc[j], 0, 0, 0);
      acc[j] = __builtin_amdgcn_mfma_f32_16x16x32_bf16(al, bh, acc[j], 0, 0, 0);
    }
  }

  // epilogue: C/D layout col=lane&15, row=quad*4+reg
#pragma unroll
  for (int j = 0; j < TJ; j++) {
    int n = bn + wc + j * 16 + l16;
    float bv = BIAS ? bias[n] : 0.f;
#pragma unroll
    for (int r = 0; r < 4; r++) {
      int m = bm + wr + quad * 4 + r;
      C[(size_t)m * N + n] = acc[j][r] + bv;
    }
  }
}

// ---------------------------------------------------------------------------
// Fused Fourier attention, key-split x2. Grid (32, H, B): x = qc*2 + ks.
// 512 thr = 8 waves, 2 queries/wave, 16 queries/block, 128 keys (2 tiles).
// __launch_bounds__(512, 4): empirical VGPR cap 64 on this compiler; the
// round-4 body compiled to 48 under it. Body kept register-lean (no XOR
// swizzle address math -- rounds 5-7 exceeded 64 and spilled ~1 GB/launch).
// Conflict strategy: scalar b32 LDS reads with lane = contiguous index
// (conflict-free at any stride) instead of padded/swizzled b128:
//   K stored transposed KT[d][key] (pad 65)  -> score reads KT[d][lane]
//   V stored natural   Vn[key][d]  (pad 68)  -> AV    reads Vn[j][lane]
//   Q / A4 reads are same-address broadcasts (free).
// Staging pre-scales q'=R*q, k'=R*k; score=(PI sin D/PI D)*R^64.
// Bitwise q_d==k_d -> den==0: guarded division (|sin x|<=|x| => num==0 too).
// ---------------------------------------------------------------------------
__global__ __launch_bounds__(512, 4) void fourier_attn(
    const float* __restrict__ qkv, const float* __restrict__ paramR,
    float* __restrict__ acc0, float* __restrict__ acc1,
    float* __restrict__ S0, float* __restrict__ S1) {
  __shared__ float KT[DH][65];    // [dim][key], pad 65: scatter writes 2-way
  __shared__ float Vn[64][68];    // [key][dim], pad 68: 16B-aligned rows
  __shared__ float Qs[16][DH];    // scaled queries
  __shared__ float A4[8][64][2];  // [wave][key][q]

  const int t = threadIdx.x;
  const int lane = t & 63;
  const int wv = t >> 6;
  const int qc = blockIdx.x >> 1;
  const int ks = blockIdx.x & 1;
  const int h = blockIdx.y;
  const int b = blockIdx.z;
  const float R = paramR[0];
  float R64;  // R^64 by 6 squarings
  {
    float r2 = R * R, r4 = r2 * r2, r8 = r4 * r4, r16 = r8 * r8;
    float r32 = r16 * r16;
    R64 = r32 * r32;
  }

  const float* base = qkv + (size_t)b * NN * (3 * CC) + h * DH;

  if (t < 256) {
    int r = t >> 4;
    int c4 = (t & 15) << 2;
    float4 qv = *(const float4*)(base + (size_t)(qc * 16 + r) * (3 * CC) + c4);
    qv.x *= R; qv.y *= R; qv.z *= R; qv.w *= R;
    *(float4*)&Qs[r][c4] = qv;
  }

  const int qi0 = wv * 2, qi1 = wv * 2 + 1;
  float Sp[2] = {0.f, 0.f};
  float oacc[2] = {0.f, 0.f};

  for (int jt2 = 0; jt2 < 2; jt2++) {
    const int jt = ks * 2 + jt2;
    __syncthreads();
    // ---- stage K (transposed, scaled) and V (natural): 1024 float4 slots
#pragma unroll
    for (int u0 = 0; u0 < 2; u0++) {
      int u = t + 512 * u0;
      int r = u >> 4;          // key row 0..63
      int c4 = (u & 15) << 2;  // dim 0..60
      const float* krow = base + (size_t)(jt * 64 + r) * (3 * CC) + CC;
      float4 kv = *(const float4*)(krow + c4);
      KT[c4 + 0][r] = kv.x * R;
      KT[c4 + 1][r] = kv.y * R;
      KT[c4 + 2][r] = kv.z * R;
      KT[c4 + 3][r] = kv.w * R;
      const float* vrow = base + (size_t)(jt * 64 + r) * (3 * CC) + 2 * CC;
      *(float4*)&Vn[r][c4] = *(const float4*)(vrow + c4);
    }
    __syncthreads();

    // ---- score phase: lane = key
    float nm[2][2] = {{1.f, 1.f}, {1.f, 1.f}};
    float dn[2][2] = {{1.f, 1.f}, {1.f, 1.f}};
#pragma unroll
    for (int d4 = 0; d4 < 16; d4++) {
      const int p = d4 & 1;
      float ka[4];
#pragma unroll
      for (int i = 0; i < 4; i++) ka[i] = KT[4 * d4 + i][lane];  // free
      float4 qa = *(const float4*)&Qs[qi0][d4 << 2];  // broadcast
      float4 qb = *(const float4*)&Qs[qi1][d4 << 2];  // broadcast
      float q0a[4] = {qa.x, qa.y, qa.z, qa.w};
      float q1a[4] = {qb.x, qb.y, qb.z, qb.w};
#pragma unroll
      for (int j = 0; j < 4; j++) {
        float D0 = q0a[j] - ka[j];  // = R*(q-k)
        float D1 = q1a[j] - ka[j];
        nm[0][p] *= __sinf(D0);
        dn[0][p] *= D0;
        nm[1][p] *= __sinf(D1);
        dn[1][p] *= D1;
      }
    }
#pragma unroll
    for (int q = 0; q < 2; q++) {
      float num = nm[q][0] * nm[q][1];
      float den = dn[q][0] * dn[q][1];
      float sc = (den != 0.f) ? (num / den) * R64 : 0.f;
      float s2 = sc * sc;
      float a4 = s2 * s2;
      Sp[q] += a4;
      A4[wv][lane][q] = a4;  // same-wave RAW with AV below
    }

    // ---- AV phase: lane = dim; 2 keys per iteration
#pragma unroll 8
    for (int j2 = 0; j2 < 32; j2++) {
      float v0 = Vn[2 * j2 + 0][lane];                 // free
      float v1 = Vn[2 * j2 + 1][lane];                 // free
      float4 a = *(const float4*)&A4[wv][2 * j2][0];   // broadcast 16B
      oacc[0] = fmaf(a.x, v0, oacc[0]);
      oacc[1] = fmaf(a.y, v0, oacc[1]);
      oacc[0] = fmaf(a.z, v1, oacc[0]);
      oacc[1] = fmaf(a.w, v1, oacc[1]);
    }
  }

  // ---- store partials
  float* accp = ks ? acc1 : acc0;
  float* Sg = ks ? S1 : S0;
#pragma unroll
  for (int q = 0; q < 2; q++) {
    float s = Sp[q];
#pragma unroll
    for (int off = 32; off > 0; off >>= 1) s += __shfl_xor(s, off, 64);
    int n = qc * 16 + wv * 2 + q;
    accp[(size_t)(b * NN + n) * CC + h * DH + lane] = oacc[q];
    if (lane == 0) Sg[((b * HH + h) << 8) + n] = s;
  }
}

// ---------------------------------------------------------------------------
// Combine key-split partials, normalize, emit hi/lo bf16 for the proj GEMM.
// ---------------------------------------------------------------------------
__global__ __launch_bounds__(256) void normalize_hilo(
    const float* __restrict__ acc0, const float* __restrict__ acc1,
    const float* __restrict__ S0, const float* __restrict__ S1,
    unsigned short* __restrict__ aoh, unsigned short* __restrict__ aol) {
  int idx = (blockIdx.x * 256 + threadIdx.x) * 4;
  int m = idx >> 9;
  int c = idx & 511;
  int b = m >> 8, n = m & 255, h = c >> 6;
  int si = ((b * HH + h) << 8) + n;
  float s = S0[si] + S1[si] + 1e-6f;
  float4 a = *(const float4*)(acc0 + idx);
  float4 a1 = *(const float4*)(acc1 + idx);
  float oa[4] = {(a.x + a1.x) / s, (a.y + a1.y) / s, (a.z + a1.z) / s,
                 (a.w + a1.w) / s};
  ushort4 hv, lv;
  unsigned short* hp = (unsigned short*)&hv;
  unsigned short* lp = (unsigned short*)&lv;
#pragma unroll
  for (int j = 0; j < 4; j++) {
    unsigned short hb = f2bf(oa[j]);
    hp[j] = hb;
    lp[j] = f2bf(oa[j] - bf2f(hb));
  }
  *(ushort4*)(aoh + idx) = hv;
  *(ushort4*)(aol + idx) = lv;
}

// ---------------------------------------------------------------------------
extern "C" void kernel_launch(void* const* d_in, const int* in_sizes, int n_in,
                              void* d_out, int out_size, void* d_ws,
                              size_t ws_size, hipStream_t stream) {
  const float* x = (const float*)d_in[0];       // (B,N,C)
  const float* w_qkv = (const float*)d_in[1];   // (3C, C)
  const float* w_proj = (const float*)d_in[2];  // (C, C)
  const float* b_proj = (const float*)d_in[3];  // (C,)
  const float* paramR = (const float*)d_in[4];  // (1,)
  float* outp = (float*)d_out;                  // (B,N,C)

  const int nX = BB * NN * CC;   // 524288
  const int nWq = 3 * CC * CC;   // 786432
  const int nWp = CC * CC;       // 262144

  // ws layout (shorts), ~14.7 MB total:
  unsigned short* xh = (unsigned short*)d_ws;
  unsigned short* xl = xh + nX;
  unsigned short* wqh = xl + nX;
  unsigned short* wql = wqh + nWq;
  unsigned short* wph = wql + nWq;
  unsigned short* wpl = wph + nWp;
  unsigned short* aoh = wpl + nWp;
  unsigned short* aol = aoh + nX;
  float* qkv_ws = (float*)(aol + nX);  // 1024*1536 fp32

  // acc/S alias the xh..wql region (dead after the qkv GEMM, rewritten
  // in-order on every replay): 2*nX + 16K floats < that region's 2.6M shorts.
  float* acc0 = (float*)d_ws;
  float* acc1 = acc0 + nX;
  float* S0 = acc1 + nX;
  float* S1 = S0 + BB * HH * NN;

  // 1) hi/lo conversions (single launch)
  cvt_all<<<(nX + nWq + nWp) / 1024, 256, 0, stream>>>(
      x, w_qkv, w_proj, xh, xl, wqh, wql, wph, wpl);

  // 2) qkv = x @ w_qkv^T : M=1024, N=1536, K=512; 32x64 tiles -> 768 blocks
  gemm_mfma<2, false><<<dim3(3 * CC / 64, BB * NN / 32), 256, 0, stream>>>(
      xh, xl, wqh, wql, nullptr, qkv_ws, BB * NN, 3 * CC, CC);

  // 3) fused fourier attention, key-split x2 -> partial acc/S
  fourier_attn<<<dim3(32, HH, BB), 512, 0, stream>>>(qkv_ws, paramR, acc0,
                                                     acc1, S0, S1);

  // 4) combine + normalize + hi/lo split
  normalize_hilo<<<nX / 1024, 256, 0, stream>>>(acc0, acc1, S0, S1, aoh, aol);

  // 5) out = attn @ w_proj^T + b_proj : 32x32 tiles -> 512 blocks
  gemm_mfma<1, true><<<dim3(CC / 32, BB * NN / 32), 256, 0, stream>>>(
      aoh, aol, wph, wpl, b_proj, outp, BB * NN, CC, CC);
}